// Round 4
// baseline (526.105 us; speedup 1.0000x reference)
//
#include <hip/hip_runtime.h>
#include <cstdint>
#include <cstddef>

// ---------- types / helpers ----------
typedef float f32x4 __attribute__((ext_vector_type(4)));
typedef __bf16 bf16x8 __attribute__((ext_vector_type(8)));

__device__ __forceinline__ float b2f(unsigned short u) {
    union { unsigned int i; float f; } z; z.i = ((unsigned int)u) << 16; return z.f;
}
__device__ __forceinline__ unsigned short f2b(float f) {
    union { float f; unsigned int i; } z; z.f = f;
    unsigned int x = z.i;
    return (unsigned short)((x + 0x7FFFu + ((x >> 16) & 1u)) >> 16);
}

static constexpr int C = 128;
static constexpr int NP = 16384;      // H*W
static constexpr int NH = 8;

// ---------- weight pack: fp32 -> bf16 ----------
struct Ptr11 { const float* p[11]; };
__constant__ int kWN[11]   = {128, 128, 8, 49152, 3456, 16384, 128, 128, 65536, 4608, 32768};
__constant__ int kWOff[11] = {0, 128, 256, 272, 49424, 52880, 69264, 69392, 69520, 135056, 139664};
static constexpr int kWTotal = 172432;

__global__ __launch_bounds__(256)
void cvt_w_kernel(Ptr11 P, unsigned short* __restrict__ dst)
{
    int seg = blockIdx.y;
    int n = kWN[seg];
    int i = blockIdx.x * 256 + threadIdx.x;
    if (i >= n) return;
    dst[kWOff[seg] + i] = f2b(P.p[seg][i]);
}

// ---------- LayerNorm over channel dim (fp32 in, bf16 out) ----------
__global__ __launch_bounds__(256)
void ln_kernel(const float* __restrict__ x, const unsigned short* __restrict__ g,
               const unsigned short* __restrict__ beta, unsigned short* __restrict__ y)
{
    int p = blockIdx.x * 256 + threadIdx.x;     // over nb*NP
    int b = p >> 14;
    int n = p & (NP - 1);
    size_t base = (size_t)b * C * NP + n;
    float s = 0.f, s2 = 0.f;
    for (int c = 0; c < C; ++c) {
        float v = x[base + (size_t)c * NP];
        s += v; s2 += v * v;
    }
    float mu = s * (1.0f / C);
    float var = s2 * (1.0f / C) - mu * mu;
    float rs = rsqrtf(fmaxf(var, 0.f) + 1e-5f);
    for (int c = 0; c < C; ++c) {
        float v = x[base + (size_t)c * NP];
        float o = (v - mu) * rs * b2f(g[c]) + b2f(beta[c]);
        y[base + (size_t)c * NP] = f2b(o);
    }
}

// ---------- 1x1 conv GEMM: out[b,co,n] = sum_k W[co,k] * X[b,k,n] ----------
// EPI 0: Out is bf16, store f2b(acc). EPI 1: Out is fp32, store Res_f32 + acc.
template <int K, int EPI>
__global__ __launch_bounds__(256)
void gemm_pconv(const unsigned short* __restrict__ W,   // (Cout, K) bf16
                const unsigned short* __restrict__ X,   // (nb, K, NP) bf16
                void* __restrict__ Out,                 // (nb, Cout, NP)
                const float* __restrict__ Res,          // fp32 residual or null
                int Cout)
{
    __shared__ unsigned short Bs[32][128];
    const int tid = threadIdx.x;
    const int b = blockIdx.z;
    const int n0 = blockIdx.x * 128;
    const int m0 = blockIdx.y * 128;
    const unsigned short* Xb = X + (size_t)b * K * NP;
    const int wid = tid >> 6;
    const int lane = tid & 63;
    const int ln16 = lane & 15;
    const int quad = lane >> 4;
    const int wy = wid >> 1;      // m half
    const int wx = wid & 1;       // n half

    f32x4 acc[4][4];
    #pragma unroll
    for (int i = 0; i < 4; ++i)
        #pragma unroll
        for (int j = 0; j < 4; ++j)
            acc[i][j] = f32x4{0.f, 0.f, 0.f, 0.f};

    for (int k0 = 0; k0 < K; k0 += 32) {
        #pragma unroll
        for (int r = 0; r < 2; ++r) {
            int flat = tid + r * 256;
            int kk = flat >> 4;
            int nn = (flat & 15) * 8;
            uint4 v = *(const uint4*)(Xb + (size_t)(k0 + kk) * NP + n0 + nn);
            *(uint4*)(&Bs[kk][nn]) = v;
        }
        __syncthreads();

        bf16x8 afr[4];
        #pragma unroll
        for (int mt = 0; mt < 4; ++mt) {
            int m = m0 + wy * 64 + mt * 16 + ln16;
            uint4 v = *(const uint4*)(W + (size_t)m * K + k0 + quad * 8);
            afr[mt] = *(bf16x8*)&v;
        }
        bf16x8 bfr[4];
        #pragma unroll
        for (int nt = 0; nt < 4; ++nt) {
            int n = wx * 64 + nt * 16 + ln16;
            union { bf16x8 v; unsigned short u[8]; } tmp;
            #pragma unroll
            for (int j = 0; j < 8; ++j) tmp.u[j] = Bs[quad * 8 + j][n];
            bfr[nt] = tmp.v;
        }
        #pragma unroll
        for (int mt = 0; mt < 4; ++mt)
            #pragma unroll
            for (int nt = 0; nt < 4; ++nt)
                acc[mt][nt] = __builtin_amdgcn_mfma_f32_16x16x32_bf16(
                    afr[mt], bfr[nt], acc[mt][nt], 0, 0, 0);
        __syncthreads();
    }

    // epilogue: D row = quad*4+reg, col = lane&15
    size_t outbase = (size_t)b * Cout * NP;
    #pragma unroll
    for (int mt = 0; mt < 4; ++mt) {
        #pragma unroll
        for (int nt = 0; nt < 4; ++nt) {
            int co0 = m0 + wy * 64 + mt * 16 + quad * 4;
            int n = n0 + wx * 64 + nt * 16 + ln16;
            #pragma unroll
            for (int r = 0; r < 4; ++r) {
                float v = acc[mt][nt][r];
                size_t idx = outbase + (size_t)(co0 + r) * NP + n;
                if (EPI == 0) ((unsigned short*)Out)[idx] = f2b(v);
                else          ((float*)Out)[idx] = Res[idx] + v;
            }
        }
    }
}

// ---------- depthwise 3x3, SAME (zero) padding ----------
__global__ __launch_bounds__(256)
void dwconv3_kernel(const unsigned short* __restrict__ in,
                    const unsigned short* __restrict__ w9,
                    unsigned short* __restrict__ out, int CH)
{
    int p = blockIdx.x * 256 + threadIdx.x;   // nb*CH*NP
    int n = p & (NP - 1);
    int x = n & 127;
    int y = (n >> 7) & 127;
    int bc = p >> 14;
    int c = bc % CH;
    const unsigned short* base = in + (size_t)bc * NP;
    float acc = 0.f;
    #pragma unroll
    for (int dy = -1; dy <= 1; ++dy) {
        #pragma unroll
        for (int dx = -1; dx <= 1; ++dx) {
            int yy = y + dy, xx = x + dx;
            if (yy >= 0 && yy < 128 && xx >= 0 && xx < 128)
                acc += b2f(base[yy * 128 + xx]) * b2f(w9[c * 9 + (dy + 1) * 3 + (dx + 1)]);
        }
    }
    out[p] = f2b(acc);
}

// ---------- fused depthwise 3x3 + exact-GELU gate (GDFN) ----------
__global__ __launch_bounds__(256)
void dwgelu_kernel(const unsigned short* __restrict__ hdn,
                   const unsigned short* __restrict__ w9,
                   unsigned short* __restrict__ g)
{
    int p = blockIdx.x * 256 + threadIdx.x;   // nb*256*NP
    int n = p & (NP - 1);
    int x = n & 127;
    int y = (n >> 7) & 127;
    int bc = p >> 14;
    int c = bc & 255;
    int b = bc >> 8;
    const unsigned short* base1 = hdn + ((size_t)b * 512 + c) * NP;
    const unsigned short* base2 = base1 + (size_t)256 * NP;
    float a1 = 0.f, a2 = 0.f;
    #pragma unroll
    for (int dy = -1; dy <= 1; ++dy) {
        #pragma unroll
        for (int dx = -1; dx <= 1; ++dx) {
            int yy = y + dy, xx = x + dx;
            if (yy >= 0 && yy < 128 && xx >= 0 && xx < 128) {
                int t = (dy + 1) * 3 + (dx + 1);
                a1 += b2f(base1[yy * 128 + xx]) * b2f(w9[c * 9 + t]);
                a2 += b2f(base2[yy * 128 + xx]) * b2f(w9[(c + 256) * 9 + t]);
            }
        }
    }
    float ge = 0.5f * a1 * (1.0f + erff(a1 * 0.70710678118654752f));
    g[p] = f2b(ge * a2);
}

// ---------- per-(b, qkv-channel<256) L2 norms over NP ----------
__global__ __launch_bounds__(256)
void sumsq_kernel(const unsigned short* __restrict__ qkv, float* __restrict__ norms)
{
    int ch = blockIdx.x;   // 0..255 (q: 0..127, k: 128..255)
    int b = blockIdx.y;
    const unsigned short* p = qkv + ((size_t)b * 384 + ch) * NP;
    float s = 0.f;
    for (int i = threadIdx.x; i < NP; i += 256) {
        float v = b2f(p[i]);
        s += v * v;
    }
    #pragma unroll
    for (int o = 32; o > 0; o >>= 1) s += __shfl_down(s, o, 64);
    __shared__ float ws4[4];
    if ((threadIdx.x & 63) == 0) ws4[threadIdx.x >> 6] = s;
    __syncthreads();
    if (threadIdx.x == 0) {
        float t = ws4[0] + ws4[1] + ws4[2] + ws4[3];
        norms[b * 256 + ch] = fmaxf(sqrtf(t), 1e-12f);
    }
}

// ---------- Gram partials: Spart[b,h,slot,dq,dk], slot = sp*4+wid ----------
__global__ __launch_bounds__(256)
void gram_kernel(const unsigned short* __restrict__ qkv, float* __restrict__ Spart)
{
    int h = blockIdx.x, b = blockIdx.y, sp = blockIdx.z;   // sp: 0..7
    int wid = threadIdx.x >> 6, lane = threadIdx.x & 63;
    int ln16 = lane & 15, quad = lane >> 4;
    int nbase = sp * 2048 + wid * 512;
    const unsigned short* qp = qkv + ((size_t)b * 384 + h * 16 + ln16) * NP;
    const unsigned short* kp = qkv + ((size_t)b * 384 + 128 + h * 16 + ln16) * NP;
    f32x4 acc = f32x4{0.f, 0.f, 0.f, 0.f};
    for (int i = 0; i < 512; i += 32) {
        int n = nbase + i + quad * 8;
        uint4 av = *(const uint4*)(qp + n);
        uint4 bv = *(const uint4*)(kp + n);
        acc = __builtin_amdgcn_mfma_f32_16x16x32_bf16(*(bf16x8*)&av, *(bf16x8*)&bv, acc, 0, 0, 0);
    }
    float* Sp = Spart + (((size_t)(b * NH + h) * 32) + sp * 4 + wid) * 256;
    #pragma unroll
    for (int r = 0; r < 4; ++r)
        Sp[(quad * 4 + r) * 16 + ln16] = acc[r];
}

// ---------- softmax over dk of (sum Spart)/(nq*nk)*temp ----------
__global__ __launch_bounds__(256)
void softmax_kernel(const float* __restrict__ Spart, const float* __restrict__ norms,
                    const unsigned short* __restrict__ temp, float* __restrict__ P)
{
    int bh = blockIdx.x;
    int b = bh >> 3, h = bh & 7;
    int t = threadIdx.x;            // 256 = 16x16
    int dq = t >> 4, dk = t & 15;
    float sacc = 0.f;
    const float* Sp = Spart + (size_t)bh * 32 * 256;
    #pragma unroll
    for (int j = 0; j < 32; ++j) sacc += Sp[j * 256 + t];
    float nq = norms[b * 256 + h * 16 + dq];
    float nk = norms[b * 256 + 128 + h * 16 + dk];
    float v = sacc / (nq * nk) * b2f(temp[h]);
    float m = v;
    #pragma unroll
    for (int o = 8; o > 0; o >>= 1) m = fmaxf(m, __shfl_xor(m, o, 16));
    float e = __expf(v - m);
    float s = e;
    #pragma unroll
    for (int o = 8; o > 0; o >>= 1) s += __shfl_xor(s, o, 16);
    P[(size_t)bh * 256 + t] = e / s;
}

// ---------- out[b, h*16+dq, n] = sum_e P[dq,e] * v[e,n] ----------
__global__ __launch_bounds__(256)
void attnv_kernel(const float* __restrict__ P, const unsigned short* __restrict__ qkv,
                  unsigned short* __restrict__ out)
{
    __shared__ float Ps[256];
    int h = blockIdx.y, b = blockIdx.z;
    Ps[threadIdx.x] = P[((size_t)b * NH + h) * 256 + threadIdx.x];
    __syncthreads();
    int n = blockIdx.x * 256 + threadIdx.x;
    const unsigned short* vp = qkv + ((size_t)b * 384 + 256 + h * 16) * NP + n;
    float o[16];
    #pragma unroll
    for (int d = 0; d < 16; ++d) o[d] = 0.f;
    #pragma unroll
    for (int e = 0; e < 16; ++e) {
        float v = b2f(vp[(size_t)e * NP]);
        #pragma unroll
        for (int d = 0; d < 16; ++d) o[d] += Ps[d * 16 + e] * v;
    }
    unsigned short* op = out + ((size_t)b * C + h * 16) * NP + n;
    #pragma unroll
    for (int d = 0; d < 16; ++d) op[(size_t)d * NP] = f2b(o[d]);
}

// ---------- pipeline ----------
struct Bufs {
    float* xmid;            // nb*C*NP fp32 (trunk after MDTA)
    unsigned short* y;      // nb*C*NP bf16
    unsigned short* big;    // nb*512*NP bf16 (qkv1 / hdn)
    unsigned short* mid;    // nb*384*NP bf16 (qkv2 / gate out)
    float* norms;           // nb*256
    float* Spart;           // nb*NH*32*256
    float* P;               // nb*NH*256
};

static void run_pipeline(const float* x_f32, float* out_f32,
                         const unsigned short* w,    // packed bf16 weights
                         const Bufs& B, int nb, hipStream_t stream)
{
    const unsigned short* ln1_w   = w + 0;
    const unsigned short* ln1_b   = w + 128;
    const unsigned short* temp    = w + 256;
    const unsigned short* qkv_p_w = w + 272;
    const unsigned short* qkv_d_w = w + 49424;
    const unsigned short* proj_w  = w + 52880;
    const unsigned short* ln2_w   = w + 69264;
    const unsigned short* ln2_b   = w + 69392;
    const unsigned short* g1_w    = w + 69520;
    const unsigned short* gd_w    = w + 135056;
    const unsigned short* g2_w    = w + 139664;

    // ---- MDTA ----
    ln_kernel<<<nb * NP / 256, 256, 0, stream>>>(x_f32, ln1_w, ln1_b, B.y);
    gemm_pconv<128, 0><<<dim3(NP / 128, 3, nb), 256, 0, stream>>>(qkv_p_w, B.y, B.big, nullptr, 384);
    dwconv3_kernel<<<nb * 384 * NP / 256, 256, 0, stream>>>(B.big, qkv_d_w, B.mid, 384);
    sumsq_kernel<<<dim3(256, nb), 256, 0, stream>>>(B.mid, B.norms);
    gram_kernel<<<dim3(NH, nb, 8), 256, 0, stream>>>(B.mid, B.Spart);
    softmax_kernel<<<nb * NH, 256, 0, stream>>>(B.Spart, B.norms, temp, B.P);
    attnv_kernel<<<dim3(NP / 256, NH, nb), 256, 0, stream>>>(B.P, B.mid, B.y);
    gemm_pconv<128, 1><<<dim3(NP / 128, 1, nb), 256, 0, stream>>>(proj_w, B.y, B.xmid, x_f32, 128);

    // ---- GDFN ----
    ln_kernel<<<nb * NP / 256, 256, 0, stream>>>(B.xmid, ln2_w, ln2_b, B.y);
    gemm_pconv<128, 0><<<dim3(NP / 128, 4, nb), 256, 0, stream>>>(g1_w, B.y, B.big, nullptr, 512);
    dwgelu_kernel<<<nb * 256 * NP / 256, 256, 0, stream>>>(B.big, gd_w, B.mid);
    gemm_pconv<256, 1><<<dim3(NP / 128, 1, nb), 256, 0, stream>>>(g2_w, B.mid, out_f32, B.xmid, 128);
}

extern "C" void kernel_launch(void* const* d_in, const int* in_sizes, int n_in,
                              void* d_out, int out_size, void* d_ws, size_t ws_size,
                              hipStream_t stream)
{
    (void)in_sizes; (void)n_in; (void)out_size;
    const float* x = (const float*)d_in[0];
    char* ws = (char*)d_ws;

    size_t off = 0;
    unsigned short* wpack = (unsigned short*)(ws + off);
    off += (size_t)kWTotal * 2;
    off = (off + 255) & ~(size_t)255;
    size_t header = off;

    auto layout = [&](int nb, size_t o, Bufs& B) -> size_t {
        B.xmid = (float*)(ws + o);           o += (size_t)nb * C * NP * 4;
        B.y    = (unsigned short*)(ws + o);  o += (size_t)nb * C * NP * 2;
        B.big  = (unsigned short*)(ws + o);  o += (size_t)nb * 512 * NP * 2;
        B.mid  = (unsigned short*)(ws + o);  o += (size_t)nb * 384 * NP * 2;
        B.norms = (float*)(ws + o);          o += (size_t)nb * 256 * 4;
        B.Spart = (float*)(ws + o);          o += (size_t)nb * NH * 32 * 256 * 4;
        B.P     = (float*)(ws + o);          o += (size_t)nb * NH * 256 * 4;
        return o;
    };

    // ---- convert weights fp32 -> packed bf16 ----
    Ptr11 P;
    for (int i = 0; i < 11; ++i) P.p[i] = (const float*)d_in[i + 1];
    cvt_w_kernel<<<dim3(256, 11), 256, 0, stream>>>(P, wpack);

    Bufs Bfull;
    size_t need_full = layout(4, header, Bfull);

    if (ws_size >= need_full) {
        run_pipeline(x, (float*)d_out, wpack, Bfull, 4, stream);
    } else {
        Bufs B1;
        layout(1, header, B1);
        for (int b = 0; b < 4; ++b) {
            run_pipeline(x + (size_t)b * C * NP,
                         (float*)d_out + (size_t)b * C * NP,
                         wpack, B1, 1, stream);
        }
    }
}

// Round 5
// 391.418 us; speedup vs baseline: 1.3441x; 1.3441x over previous
//
#include <hip/hip_runtime.h>
#include <cstdint>
#include <cstddef>

// ---------- types / helpers ----------
typedef float f32x4 __attribute__((ext_vector_type(4)));
typedef __bf16 bf16x8 __attribute__((ext_vector_type(8)));

__device__ __forceinline__ float b2f(unsigned short u) {
    union { unsigned int i; float f; } z; z.i = ((unsigned int)u) << 16; return z.f;
}
__device__ __forceinline__ unsigned short f2b(float f) {
    union { float f; unsigned int i; } z; z.f = f;
    unsigned int x = z.i;
    return (unsigned short)((x + 0x7FFFu + ((x >> 16) & 1u)) >> 16);
}

static constexpr int C = 128;
static constexpr int NP = 16384;      // H*W
static constexpr int NH = 8;

// ---------- weight pack: fp32 -> bf16 ----------
struct Ptr11 { const float* p[11]; };
__constant__ int kWN[11]   = {128, 128, 8, 49152, 3456, 16384, 128, 128, 65536, 4608, 32768};
__constant__ int kWOff[11] = {0, 128, 256, 272, 49424, 52880, 69264, 69392, 69520, 135056, 139664};
static constexpr int kWTotal = 172432;

__global__ __launch_bounds__(256)
void cvt_w_kernel(Ptr11 P, unsigned short* __restrict__ dst)
{
    int seg = blockIdx.y;
    int n = kWN[seg];
    int i = blockIdx.x * 256 + threadIdx.x;
    if (i >= n) return;
    dst[kWOff[seg] + i] = f2b(P.p[seg][i]);
}

// ---------- LayerNorm over channel dim (fp32 in, bf16 out) ----------
__global__ __launch_bounds__(256)
void ln_kernel(const float* __restrict__ x, const unsigned short* __restrict__ g,
               const unsigned short* __restrict__ beta, unsigned short* __restrict__ y)
{
    int p = blockIdx.x * 256 + threadIdx.x;     // over nb*NP
    int b = p >> 14;
    int n = p & (NP - 1);
    size_t base = (size_t)b * C * NP + n;
    float s = 0.f, s2 = 0.f;
    for (int c = 0; c < C; ++c) {
        float v = x[base + (size_t)c * NP];
        s += v; s2 += v * v;
    }
    float mu = s * (1.0f / C);
    float var = s2 * (1.0f / C) - mu * mu;
    float rs = rsqrtf(fmaxf(var, 0.f) + 1e-5f);
    for (int c = 0; c < C; ++c) {
        float v = x[base + (size_t)c * NP];
        float o = (v - mu) * rs * b2f(g[c]) + b2f(beta[c]);
        y[base + (size_t)c * NP] = f2b(o);
    }
}

// ---------- 1x1 conv GEMM: out[b,co,n] = sum_k W[co,k] * X[b,k,n] ----------
// EPI 0: Out is bf16, store f2b(acc). EPI 1: Out is fp32, store Res_f32 + acc.
template <int K, int EPI>
__global__ __launch_bounds__(256)
void gemm_pconv(const unsigned short* __restrict__ W,   // (Cout, K) bf16
                const unsigned short* __restrict__ X,   // (nb, K, NP) bf16
                void* __restrict__ Out,                 // (nb, Cout, NP)
                const float* __restrict__ Res,          // fp32 residual or null
                int Cout)
{
    __shared__ unsigned short Bs[32][128];
    const int tid = threadIdx.x;
    const int b = blockIdx.z;
    const int n0 = blockIdx.x * 128;
    const int m0 = blockIdx.y * 128;
    const unsigned short* Xb = X + (size_t)b * K * NP;
    const int wid = tid >> 6;
    const int lane = tid & 63;
    const int ln16 = lane & 15;
    const int quad = lane >> 4;
    const int wy = wid >> 1;      // m half
    const int wx = wid & 1;       // n half

    f32x4 acc[4][4];
    #pragma unroll
    for (int i = 0; i < 4; ++i)
        #pragma unroll
        for (int j = 0; j < 4; ++j)
            acc[i][j] = f32x4{0.f, 0.f, 0.f, 0.f};

    for (int k0 = 0; k0 < K; k0 += 32) {
        #pragma unroll
        for (int r = 0; r < 2; ++r) {
            int flat = tid + r * 256;
            int kk = flat >> 4;
            int nn = (flat & 15) * 8;
            uint4 v = *(const uint4*)(Xb + (size_t)(k0 + kk) * NP + n0 + nn);
            *(uint4*)(&Bs[kk][nn]) = v;
        }
        __syncthreads();

        bf16x8 afr[4];
        #pragma unroll
        for (int mt = 0; mt < 4; ++mt) {
            int m = m0 + wy * 64 + mt * 16 + ln16;
            uint4 v = *(const uint4*)(W + (size_t)m * K + k0 + quad * 8);
            afr[mt] = *(bf16x8*)&v;
        }
        bf16x8 bfr[4];
        #pragma unroll
        for (int nt = 0; nt < 4; ++nt) {
            int n = wx * 64 + nt * 16 + ln16;
            union { bf16x8 v; unsigned short u[8]; } tmp;
            #pragma unroll
            for (int j = 0; j < 8; ++j) tmp.u[j] = Bs[quad * 8 + j][n];
            bfr[nt] = tmp.v;
        }
        #pragma unroll
        for (int mt = 0; mt < 4; ++mt)
            #pragma unroll
            for (int nt = 0; nt < 4; ++nt)
                acc[mt][nt] = __builtin_amdgcn_mfma_f32_16x16x32_bf16(
                    afr[mt], bfr[nt], acc[mt][nt], 0, 0, 0);
        __syncthreads();
    }

    // epilogue: D row = quad*4+reg, col = lane&15
    size_t outbase = (size_t)b * Cout * NP;
    #pragma unroll
    for (int mt = 0; mt < 4; ++mt) {
        #pragma unroll
        for (int nt = 0; nt < 4; ++nt) {
            int co0 = m0 + wy * 64 + mt * 16 + quad * 4;
            int n = n0 + wx * 64 + nt * 16 + ln16;
            #pragma unroll
            for (int r = 0; r < 4; ++r) {
                float v = acc[mt][nt][r];
                size_t idx = outbase + (size_t)(co0 + r) * NP + n;
                if (EPI == 0) ((unsigned short*)Out)[idx] = f2b(v);
                else          ((float*)Out)[idx] = Res[idx] + v;
            }
        }
    }
}

// ---------- depthwise 3x3, SAME, vectorized: 8 output px per thread ----------
__global__ __launch_bounds__(256)
void dwconv3_kernel(const unsigned short* __restrict__ in,
                    const unsigned short* __restrict__ w9,
                    unsigned short* __restrict__ out, int CH)
{
    int t = blockIdx.x * 256 + threadIdx.x;   // nb*CH*NP/8 threads
    int xi = (t & 15) * 8;                    // x0: 0..120 step 8
    int y  = (t >> 4) & 127;
    int bc = t >> 11;                         // plane index (wave-uniform)
    int c  = bc % CH;
    const unsigned short* base = in + (size_t)bc * NP;

    float wr[9];
    #pragma unroll
    for (int i = 0; i < 9; ++i) wr[i] = b2f(w9[c * 9 + i]);

    float o[8];
    #pragma unroll
    for (int j = 0; j < 8; ++j) o[j] = 0.f;

    #pragma unroll
    for (int r = 0; r < 3; ++r) {
        int yy = y + r - 1;
        if (yy < 0 || yy > 127) continue;
        const unsigned short* row = base + yy * 128 + xi;
        union { uint4 v; unsigned short u[8]; } cv;
        cv.v = *(const uint4*)row;
        float p[10];
        p[0] = (xi > 0)   ? b2f(row[-1]) : 0.f;
        p[9] = (xi < 120) ? b2f(row[8])  : 0.f;
        #pragma unroll
        for (int j = 0; j < 8; ++j) p[j + 1] = b2f(cv.u[j]);
        #pragma unroll
        for (int j = 0; j < 8; ++j)
            o[j] += wr[r * 3 + 0] * p[j] + wr[r * 3 + 1] * p[j + 1] + wr[r * 3 + 2] * p[j + 2];
    }
    union { uint4 v; unsigned short u[8]; } res;
    #pragma unroll
    for (int j = 0; j < 8; ++j) res.u[j] = f2b(o[j]);
    *(uint4*)(out + (size_t)bc * NP + y * 128 + xi) = res.v;
}

// ---------- fused depthwise 3x3 + exact-GELU gate, 8 px per thread ----------
__global__ __launch_bounds__(256)
void dwgelu_kernel(const unsigned short* __restrict__ hdn,
                   const unsigned short* __restrict__ w9,
                   unsigned short* __restrict__ g)
{
    int t = blockIdx.x * 256 + threadIdx.x;   // nb*256*NP/8 threads
    int xi = (t & 15) * 8;
    int y  = (t >> 4) & 127;
    int bc = t >> 11;
    int c  = bc & 255;
    int b  = bc >> 8;
    const unsigned short* base1 = hdn + ((size_t)b * 512 + c) * NP;
    const unsigned short* base2 = base1 + (size_t)256 * NP;

    float w1[9], w2[9];
    #pragma unroll
    for (int i = 0; i < 9; ++i) {
        w1[i] = b2f(w9[c * 9 + i]);
        w2[i] = b2f(w9[(c + 256) * 9 + i]);
    }

    float a1[8], a2[8];
    #pragma unroll
    for (int j = 0; j < 8; ++j) { a1[j] = 0.f; a2[j] = 0.f; }

    #pragma unroll
    for (int r = 0; r < 3; ++r) {
        int yy = y + r - 1;
        if (yy < 0 || yy > 127) continue;
        const unsigned short* row1 = base1 + yy * 128 + xi;
        const unsigned short* row2 = base2 + yy * 128 + xi;
        union { uint4 v; unsigned short u[8]; } c1, c2;
        c1.v = *(const uint4*)row1;
        c2.v = *(const uint4*)row2;
        float p1[10], p2[10];
        p1[0] = (xi > 0)   ? b2f(row1[-1]) : 0.f;
        p1[9] = (xi < 120) ? b2f(row1[8])  : 0.f;
        p2[0] = (xi > 0)   ? b2f(row2[-1]) : 0.f;
        p2[9] = (xi < 120) ? b2f(row2[8])  : 0.f;
        #pragma unroll
        for (int j = 0; j < 8; ++j) { p1[j + 1] = b2f(c1.u[j]); p2[j + 1] = b2f(c2.u[j]); }
        #pragma unroll
        for (int j = 0; j < 8; ++j) {
            a1[j] += w1[r * 3 + 0] * p1[j] + w1[r * 3 + 1] * p1[j + 1] + w1[r * 3 + 2] * p1[j + 2];
            a2[j] += w2[r * 3 + 0] * p2[j] + w2[r * 3 + 1] * p2[j + 1] + w2[r * 3 + 2] * p2[j + 2];
        }
    }
    union { uint4 v; unsigned short u[8]; } res;
    #pragma unroll
    for (int j = 0; j < 8; ++j) {
        float ge = 0.5f * a1[j] * (1.0f + erff(a1[j] * 0.70710678118654752f));
        res.u[j] = f2b(ge * a2[j]);
    }
    *(uint4*)(g + (size_t)bc * NP + y * 128 + xi) = res.v;
}

// ---------- per-(b, qkv-channel<256) L2 norms over NP ----------
__global__ __launch_bounds__(256)
void sumsq_kernel(const unsigned short* __restrict__ qkv, float* __restrict__ norms)
{
    int ch = blockIdx.x;   // 0..255 (q: 0..127, k: 128..255)
    int b = blockIdx.y;
    const unsigned short* p = qkv + ((size_t)b * 384 + ch) * NP;
    float s = 0.f;
    for (int i = threadIdx.x; i < NP; i += 256) {
        float v = b2f(p[i]);
        s += v * v;
    }
    #pragma unroll
    for (int o = 32; o > 0; o >>= 1) s += __shfl_down(s, o, 64);
    __shared__ float ws4[4];
    if ((threadIdx.x & 63) == 0) ws4[threadIdx.x >> 6] = s;
    __syncthreads();
    if (threadIdx.x == 0) {
        float t = ws4[0] + ws4[1] + ws4[2] + ws4[3];
        norms[b * 256 + ch] = fmaxf(sqrtf(t), 1e-12f);
    }
}

// ---------- Gram partials: Spart[b,h,slot,dq,dk], slot = sp*4+wid ----------
__global__ __launch_bounds__(256)
void gram_kernel(const unsigned short* __restrict__ qkv, float* __restrict__ Spart)
{
    int h = blockIdx.x, b = blockIdx.y, sp = blockIdx.z;   // sp: 0..7
    int wid = threadIdx.x >> 6, lane = threadIdx.x & 63;
    int ln16 = lane & 15, quad = lane >> 4;
    int nbase = sp * 2048 + wid * 512;
    const unsigned short* qp = qkv + ((size_t)b * 384 + h * 16 + ln16) * NP;
    const unsigned short* kp = qkv + ((size_t)b * 384 + 128 + h * 16 + ln16) * NP;
    f32x4 acc = f32x4{0.f, 0.f, 0.f, 0.f};
    for (int i = 0; i < 512; i += 32) {
        int n = nbase + i + quad * 8;
        uint4 av = *(const uint4*)(qp + n);
        uint4 bv = *(const uint4*)(kp + n);
        acc = __builtin_amdgcn_mfma_f32_16x16x32_bf16(*(bf16x8*)&av, *(bf16x8*)&bv, acc, 0, 0, 0);
    }
    float* Sp = Spart + (((size_t)(b * NH + h) * 32) + sp * 4 + wid) * 256;
    #pragma unroll
    for (int r = 0; r < 4; ++r)
        Sp[(quad * 4 + r) * 16 + ln16] = acc[r];
}

// ---------- softmax over dk of (sum Spart)/(nq*nk)*temp ----------
__global__ __launch_bounds__(256)
void softmax_kernel(const float* __restrict__ Spart, const float* __restrict__ norms,
                    const unsigned short* __restrict__ temp, float* __restrict__ P)
{
    int bh = blockIdx.x;
    int b = bh >> 3, h = bh & 7;
    int t = threadIdx.x;            // 256 = 16x16
    int dq = t >> 4, dk = t & 15;
    float sacc = 0.f;
    const float* Sp = Spart + (size_t)bh * 32 * 256;
    #pragma unroll
    for (int j = 0; j < 32; ++j) sacc += Sp[j * 256 + t];
    float nq = norms[b * 256 + h * 16 + dq];
    float nk = norms[b * 256 + 128 + h * 16 + dk];
    float v = sacc / (nq * nk) * b2f(temp[h]);
    float m = v;
    #pragma unroll
    for (int o = 8; o > 0; o >>= 1) m = fmaxf(m, __shfl_xor(m, o, 16));
    float e = __expf(v - m);
    float s = e;
    #pragma unroll
    for (int o = 8; o > 0; o >>= 1) s += __shfl_xor(s, o, 16);
    P[(size_t)bh * 256 + t] = e / s;
}

// ---------- out[b, h*16+dq, n..n+3] = sum_e P[dq,e] * v[e,n..n+3] ----------
__global__ __launch_bounds__(256)
void attnv_kernel(const float* __restrict__ P, const unsigned short* __restrict__ qkv,
                  unsigned short* __restrict__ out)
{
    __shared__ float Ps[256];
    int h = blockIdx.y, b = blockIdx.z;
    Ps[threadIdx.x] = P[((size_t)b * NH + h) * 256 + threadIdx.x];
    __syncthreads();
    int n = (blockIdx.x * 256 + threadIdx.x) * 4;     // grid.x = NP/1024
    const unsigned short* vp = qkv + ((size_t)b * 384 + 256 + h * 16) * NP + n;
    float o[16][4];
    #pragma unroll
    for (int d = 0; d < 16; ++d)
        #pragma unroll
        for (int j = 0; j < 4; ++j) o[d][j] = 0.f;
    #pragma unroll
    for (int e = 0; e < 16; ++e) {
        union { uint2 v; unsigned short u[4]; } cv;
        cv.v = *(const uint2*)(vp + (size_t)e * NP);
        float v0 = b2f(cv.u[0]), v1 = b2f(cv.u[1]), v2 = b2f(cv.u[2]), v3 = b2f(cv.u[3]);
        #pragma unroll
        for (int d = 0; d < 16; ++d) {
            float p = Ps[d * 16 + e];
            o[d][0] += p * v0; o[d][1] += p * v1; o[d][2] += p * v2; o[d][3] += p * v3;
        }
    }
    unsigned short* op = out + ((size_t)b * C + h * 16) * NP + n;
    #pragma unroll
    for (int d = 0; d < 16; ++d) {
        union { uint2 v; unsigned short u[4]; } res;
        #pragma unroll
        for (int j = 0; j < 4; ++j) res.u[j] = f2b(o[d][j]);
        *(uint2*)(op + (size_t)d * NP) = res.v;
    }
}

// ---------- pipeline ----------
struct Bufs {
    float* xmid;            // nb*C*NP fp32 (trunk after MDTA)
    unsigned short* y;      // nb*C*NP bf16
    unsigned short* big;    // nb*512*NP bf16 (qkv1 / hdn)
    unsigned short* mid;    // nb*384*NP bf16 (qkv2 / gate out)
    float* norms;           // nb*256
    float* Spart;           // nb*NH*32*256
    float* P;               // nb*NH*256
};

static void run_pipeline(const float* x_f32, float* out_f32,
                         const unsigned short* w,    // packed bf16 weights
                         const Bufs& B, int nb, hipStream_t stream)
{
    const unsigned short* ln1_w   = w + 0;
    const unsigned short* ln1_b   = w + 128;
    const unsigned short* temp    = w + 256;
    const unsigned short* qkv_p_w = w + 272;
    const unsigned short* qkv_d_w = w + 49424;
    const unsigned short* proj_w  = w + 52880;
    const unsigned short* ln2_w   = w + 69264;
    const unsigned short* ln2_b   = w + 69392;
    const unsigned short* g1_w    = w + 69520;
    const unsigned short* gd_w    = w + 135056;
    const unsigned short* g2_w    = w + 139664;

    // ---- MDTA ----
    ln_kernel<<<nb * NP / 256, 256, 0, stream>>>(x_f32, ln1_w, ln1_b, B.y);
    gemm_pconv<128, 0><<<dim3(NP / 128, 3, nb), 256, 0, stream>>>(qkv_p_w, B.y, B.big, nullptr, 384);
    dwconv3_kernel<<<nb * 384 * NP / 2048, 256, 0, stream>>>(B.big, qkv_d_w, B.mid, 384);
    sumsq_kernel<<<dim3(256, nb), 256, 0, stream>>>(B.mid, B.norms);
    gram_kernel<<<dim3(NH, nb, 8), 256, 0, stream>>>(B.mid, B.Spart);
    softmax_kernel<<<nb * NH, 256, 0, stream>>>(B.Spart, B.norms, temp, B.P);
    attnv_kernel<<<dim3(NP / 1024, NH, nb), 256, 0, stream>>>(B.P, B.mid, B.y);
    gemm_pconv<128, 1><<<dim3(NP / 128, 1, nb), 256, 0, stream>>>(proj_w, B.y, B.xmid, x_f32, 128);

    // ---- GDFN ----
    ln_kernel<<<nb * NP / 256, 256, 0, stream>>>(B.xmid, ln2_w, ln2_b, B.y);
    gemm_pconv<128, 0><<<dim3(NP / 128, 4, nb), 256, 0, stream>>>(g1_w, B.y, B.big, nullptr, 512);
    dwgelu_kernel<<<nb * 256 * NP / 2048, 256, 0, stream>>>(B.big, gd_w, B.mid);
    gemm_pconv<256, 1><<<dim3(NP / 128, 1, nb), 256, 0, stream>>>(g2_w, B.mid, out_f32, B.xmid, 128);
}

extern "C" void kernel_launch(void* const* d_in, const int* in_sizes, int n_in,
                              void* d_out, int out_size, void* d_ws, size_t ws_size,
                              hipStream_t stream)
{
    (void)in_sizes; (void)n_in; (void)out_size;
    const float* x = (const float*)d_in[0];
    char* ws = (char*)d_ws;

    size_t off = 0;
    unsigned short* wpack = (unsigned short*)(ws + off);
    off += (size_t)kWTotal * 2;
    off = (off + 255) & ~(size_t)255;
    size_t header = off;

    auto layout = [&](int nb, size_t o, Bufs& B) -> size_t {
        B.xmid = (float*)(ws + o);           o += (size_t)nb * C * NP * 4;
        B.y    = (unsigned short*)(ws + o);  o += (size_t)nb * C * NP * 2;
        B.big  = (unsigned short*)(ws + o);  o += (size_t)nb * 512 * NP * 2;
        B.mid  = (unsigned short*)(ws + o);  o += (size_t)nb * 384 * NP * 2;
        B.norms = (float*)(ws + o);          o += (size_t)nb * 256 * 4;
        B.Spart = (float*)(ws + o);          o += (size_t)nb * NH * 32 * 256 * 4;
        B.P     = (float*)(ws + o);          o += (size_t)nb * NH * 256 * 4;
        return o;
    };

    // ---- convert weights fp32 -> packed bf16 ----
    Ptr11 P;
    for (int i = 0; i < 11; ++i) P.p[i] = (const float*)d_in[i + 1];
    cvt_w_kernel<<<dim3(256, 11), 256, 0, stream>>>(P, wpack);

    Bufs Bfull;
    size_t need_full = layout(4, header, Bfull);

    if (ws_size >= need_full) {
        run_pipeline(x, (float*)d_out, wpack, Bfull, 4, stream);
    } else {
        Bufs B1;
        layout(1, header, B1);
        for (int b = 0; b < 4; ++b) {
            run_pipeline(x + (size_t)b * C * NP,
                         (float*)d_out + (size_t)b * C * NP,
                         wpack, B1, 1, stream);
        }
    }
}

// Round 6
// 275.530 us; speedup vs baseline: 1.9094x; 1.4206x over previous
//
#include <hip/hip_runtime.h>
#include <cstdint>
#include <cstddef>

// ---------- types / helpers ----------
typedef float f32x4 __attribute__((ext_vector_type(4)));
typedef __bf16 bf16x8 __attribute__((ext_vector_type(8)));

__device__ __forceinline__ float b2f(unsigned short u) {
    union { unsigned int i; float f; } z; z.i = ((unsigned int)u) << 16; return z.f;
}
__device__ __forceinline__ unsigned short f2b(float f) {
    union { float f; unsigned int i; } z; z.f = f;
    unsigned int x = z.i;
    return (unsigned short)((x + 0x7FFFu + ((x >> 16) & 1u)) >> 16);
}

static constexpr int C = 128;
static constexpr int NP = 16384;      // H*W
static constexpr int NH = 8;

// ---------- weight pack: fp32 -> bf16 ----------
struct Ptr11 { const float* p[11]; };
__constant__ int kWN[11]   = {128, 128, 8, 49152, 3456, 16384, 128, 128, 65536, 4608, 32768};
__constant__ int kWOff[11] = {0, 128, 256, 272, 49424, 52880, 69264, 69392, 69520, 135056, 139664};
static constexpr int kWTotal = 172432;

__global__ __launch_bounds__(256)
void cvt_w_kernel(Ptr11 P, unsigned short* __restrict__ dst)
{
    int seg = blockIdx.y;
    int n = kWN[seg];
    int i = blockIdx.x * 256 + threadIdx.x;
    if (i >= n) return;
    dst[kWOff[seg] + i] = f2b(P.p[seg][i]);
}

// ---------- LayerNorm over channel dim (fp32 in, bf16 out) ----------
// Wave-transposed: lane = px(0..15) | cgrp(0..3); each lane holds 32 c-values
// in registers -> single pass over x. 16 px per wave, 64 px per block.
__global__ __launch_bounds__(256)
void ln_kernel(const float* __restrict__ x, const unsigned short* __restrict__ g,
               const unsigned short* __restrict__ beta, unsigned short* __restrict__ y)
{
    int wave = threadIdx.x >> 6;
    int lane = threadIdx.x & 63;
    int px   = lane & 15;
    int cgrp = lane >> 4;
    int pglob = blockIdx.x * 64 + wave * 16 + px;   // over nb*NP
    int b = pglob >> 14;
    int n = pglob & (NP - 1);
    const float* xb = x + (size_t)b * C * NP + n;

    float vals[32];
    float s = 0.f, s2 = 0.f;
    #pragma unroll
    for (int i = 0; i < 32; ++i) {
        float v = xb[(size_t)(cgrp + 4 * i) * NP];
        vals[i] = v;
        s += v; s2 += v * v;
    }
    s  += __shfl_xor(s, 16, 64);  s2 += __shfl_xor(s2, 16, 64);
    s  += __shfl_xor(s, 32, 64);  s2 += __shfl_xor(s2, 32, 64);
    float mu = s * (1.0f / C);
    float var = s2 * (1.0f / C) - mu * mu;
    float rs = rsqrtf(fmaxf(var, 0.f) + 1e-5f);

    unsigned short* yb = y + (size_t)b * C * NP + n;
    #pragma unroll
    for (int i = 0; i < 32; ++i) {
        int c = cgrp + 4 * i;
        float o = (vals[i] - mu) * rs * b2f(g[c]) + b2f(beta[c]);
        yb[(size_t)c * NP] = f2b(o);
    }
}

// ---------- 1x1 conv GEMM: out[b,co,n] = sum_k W[co,k] * X[b,k,n] ----------
// EPI 0: Out is bf16, store f2b(acc). EPI 1: Out is fp32, store Res_f32 + acc.
template <int K, int EPI>
__global__ __launch_bounds__(256)
void gemm_pconv(const unsigned short* __restrict__ W,   // (Cout, K) bf16
                const unsigned short* __restrict__ X,   // (nb, K, NP) bf16
                void* __restrict__ Out,                 // (nb, Cout, NP)
                const float* __restrict__ Res,          // fp32 residual or null
                int Cout)
{
    __shared__ unsigned short Bs[32][128];
    const int tid = threadIdx.x;
    const int b = blockIdx.z;
    const int n0 = blockIdx.x * 128;
    const int m0 = blockIdx.y * 128;
    const unsigned short* Xb = X + (size_t)b * K * NP;
    const int wid = tid >> 6;
    const int lane = tid & 63;
    const int ln16 = lane & 15;
    const int quad = lane >> 4;
    const int wy = wid >> 1;      // m half
    const int wx = wid & 1;       // n half

    f32x4 acc[4][4];
    #pragma unroll
    for (int i = 0; i < 4; ++i)
        #pragma unroll
        for (int j = 0; j < 4; ++j)
            acc[i][j] = f32x4{0.f, 0.f, 0.f, 0.f};

    for (int k0 = 0; k0 < K; k0 += 32) {
        #pragma unroll
        for (int r = 0; r < 2; ++r) {
            int flat = tid + r * 256;
            int kk = flat >> 4;
            int nn = (flat & 15) * 8;
            uint4 v = *(const uint4*)(Xb + (size_t)(k0 + kk) * NP + n0 + nn);
            *(uint4*)(&Bs[kk][nn]) = v;
        }
        __syncthreads();

        bf16x8 afr[4];
        #pragma unroll
        for (int mt = 0; mt < 4; ++mt) {
            int m = m0 + wy * 64 + mt * 16 + ln16;
            uint4 v = *(const uint4*)(W + (size_t)m * K + k0 + quad * 8);
            afr[mt] = *(bf16x8*)&v;
        }
        bf16x8 bfr[4];
        #pragma unroll
        for (int nt = 0; nt < 4; ++nt) {
            int n = wx * 64 + nt * 16 + ln16;
            union { bf16x8 v; unsigned short u[8]; } tmp;
            #pragma unroll
            for (int j = 0; j < 8; ++j) tmp.u[j] = Bs[quad * 8 + j][n];
            bfr[nt] = tmp.v;
        }
        #pragma unroll
        for (int mt = 0; mt < 4; ++mt)
            #pragma unroll
            for (int nt = 0; nt < 4; ++nt)
                acc[mt][nt] = __builtin_amdgcn_mfma_f32_16x16x32_bf16(
                    afr[mt], bfr[nt], acc[mt][nt], 0, 0, 0);
        __syncthreads();
    }

    // epilogue: D row = quad*4+reg, col = lane&15
    size_t outbase = (size_t)b * Cout * NP;
    #pragma unroll
    for (int mt = 0; mt < 4; ++mt) {
        #pragma unroll
        for (int nt = 0; nt < 4; ++nt) {
            int co0 = m0 + wy * 64 + mt * 16 + quad * 4;
            int n = n0 + wx * 64 + nt * 16 + ln16;
            #pragma unroll
            for (int r = 0; r < 4; ++r) {
                float v = acc[mt][nt][r];
                size_t idx = outbase + (size_t)(co0 + r) * NP + n;
                if (EPI == 0) ((unsigned short*)Out)[idx] = f2b(v);
                else          ((float*)Out)[idx] = Res[idx] + v;
            }
        }
    }
}

// ---------- depthwise 3x3, SAME: 8 px/thread, halos via shuffles ----------
__global__ __launch_bounds__(256)
void dwconv3_kernel(const unsigned short* __restrict__ in,
                    const unsigned short* __restrict__ w9,
                    unsigned short* __restrict__ out, int CH)
{
    int t = blockIdx.x * 256 + threadIdx.x;   // nb*CH*NP/8 threads
    int xi = (t & 15) * 8;
    int y  = (t >> 4) & 127;
    int bc = t >> 11;
    int c  = bc % CH;
    const unsigned short* base = in + (size_t)bc * NP + y * 128 + xi;

    float wr[9];
    #pragma unroll
    for (int i = 0; i < 9; ++i) wr[i] = b2f(w9[c * 9 + i]);

    uint4 rv0 = uint4{0,0,0,0}, rv1, rv2 = uint4{0,0,0,0};
    if (y > 0)   rv0 = *(const uint4*)(base - 128);
    rv1 = *(const uint4*)(base);
    if (y < 127) rv2 = *(const uint4*)(base + 128);
    uint4 rows[3] = {rv0, rv1, rv2};

    float o[8];
    #pragma unroll
    for (int j = 0; j < 8; ++j) o[j] = 0.f;

    #pragma unroll
    for (int r = 0; r < 3; ++r) {
        union { uint4 v; unsigned short u[8]; } cv; cv.v = rows[r];
        int lh = __shfl_up((int)cv.u[7], 1, 16);
        int rh = __shfl_down((int)cv.u[0], 1, 16);
        float p[10];
        p[0] = (xi > 0)   ? b2f((unsigned short)lh) : 0.f;
        p[9] = (xi < 120) ? b2f((unsigned short)rh) : 0.f;
        #pragma unroll
        for (int j = 0; j < 8; ++j) p[j + 1] = b2f(cv.u[j]);
        #pragma unroll
        for (int j = 0; j < 8; ++j)
            o[j] += wr[r * 3] * p[j] + wr[r * 3 + 1] * p[j + 1] + wr[r * 3 + 2] * p[j + 2];
    }
    union { uint4 v; unsigned short u[8]; } res;
    #pragma unroll
    for (int j = 0; j < 8; ++j) res.u[j] = f2b(o[j]);
    *(uint4*)(out + (size_t)bc * NP + y * 128 + xi) = res.v;
}

// ---------- fused dw3x3 + fast-GELU gate, 8 px/thread, shuffle halos ----------
__global__ __launch_bounds__(256)
void dwgelu_kernel(const unsigned short* __restrict__ hdn,
                   const unsigned short* __restrict__ w9,
                   unsigned short* __restrict__ g)
{
    int t = blockIdx.x * 256 + threadIdx.x;   // nb*256*NP/8 threads
    int xi = (t & 15) * 8;
    int y  = (t >> 4) & 127;
    int bc = t >> 11;
    int c  = bc & 255;
    int b  = bc >> 8;
    const unsigned short* base1 = hdn + ((size_t)b * 512 + c) * NP + y * 128 + xi;
    const unsigned short* base2 = base1 + (size_t)256 * NP;

    float w1[9], w2[9];
    #pragma unroll
    for (int i = 0; i < 9; ++i) {
        w1[i] = b2f(w9[c * 9 + i]);
        w2[i] = b2f(w9[(c + 256) * 9 + i]);
    }

    uint4 ra0 = uint4{0,0,0,0}, ra1, ra2 = uint4{0,0,0,0};
    uint4 rb0 = uint4{0,0,0,0}, rb1, rb2 = uint4{0,0,0,0};
    if (y > 0)   { ra0 = *(const uint4*)(base1 - 128); rb0 = *(const uint4*)(base2 - 128); }
    ra1 = *(const uint4*)(base1);
    rb1 = *(const uint4*)(base2);
    if (y < 127) { ra2 = *(const uint4*)(base1 + 128); rb2 = *(const uint4*)(base2 + 128); }
    uint4 rowsA[3] = {ra0, ra1, ra2};
    uint4 rowsB[3] = {rb0, rb1, rb2};

    float a1[8], a2[8];
    #pragma unroll
    for (int j = 0; j < 8; ++j) { a1[j] = 0.f; a2[j] = 0.f; }

    #pragma unroll
    for (int r = 0; r < 3; ++r) {
        union { uint4 v; unsigned short u[8]; } c1, c2;
        c1.v = rowsA[r]; c2.v = rowsB[r];
        int lh1 = __shfl_up((int)c1.u[7], 1, 16);
        int rh1 = __shfl_down((int)c1.u[0], 1, 16);
        int lh2 = __shfl_up((int)c2.u[7], 1, 16);
        int rh2 = __shfl_down((int)c2.u[0], 1, 16);
        float p1[10], p2[10];
        p1[0] = (xi > 0)   ? b2f((unsigned short)lh1) : 0.f;
        p1[9] = (xi < 120) ? b2f((unsigned short)rh1) : 0.f;
        p2[0] = (xi > 0)   ? b2f((unsigned short)lh2) : 0.f;
        p2[9] = (xi < 120) ? b2f((unsigned short)rh2) : 0.f;
        #pragma unroll
        for (int j = 0; j < 8; ++j) { p1[j + 1] = b2f(c1.u[j]); p2[j + 1] = b2f(c2.u[j]); }
        #pragma unroll
        for (int j = 0; j < 8; ++j) {
            a1[j] += w1[r * 3] * p1[j] + w1[r * 3 + 1] * p1[j + 1] + w1[r * 3 + 2] * p1[j + 2];
            a2[j] += w2[r * 3] * p2[j] + w2[r * 3 + 1] * p2[j + 1] + w2[r * 3 + 2] * p2[j + 2];
        }
    }
    union { uint4 v; unsigned short u[8]; } res;
    #pragma unroll
    for (int j = 0; j < 8; ++j) {
        // tanh-form GELU: 0.5x(1+tanh(0.79788456(x+0.044715x^3)))
        float u = a1[j];
        float tt = u * (0.7978845608f + 0.0356774081f * u * u);
        float e = __expf(2.f * tt);
        float th = 1.f - 2.f / (e + 1.f);
        float ge = 0.5f * u * (1.f + th);
        res.u[j] = f2b(ge * a2[j]);
    }
    *(uint4*)(g + (size_t)bc * NP + y * 128 + xi) = res.v;
}

// ---------- per-(b, qkv-channel<256) L2 norms over NP ----------
__global__ __launch_bounds__(256)
void sumsq_kernel(const unsigned short* __restrict__ qkv, float* __restrict__ norms)
{
    int ch = blockIdx.x;   // 0..255 (q: 0..127, k: 128..255)
    int b = blockIdx.y;
    const unsigned short* p = qkv + ((size_t)b * 384 + ch) * NP;
    float s = 0.f;
    for (int i = threadIdx.x * 8; i < NP; i += 2048) {
        union { uint4 v; unsigned short u[8]; } cv;
        cv.v = *(const uint4*)(p + i);
        #pragma unroll
        for (int j = 0; j < 8; ++j) { float v = b2f(cv.u[j]); s += v * v; }
    }
    #pragma unroll
    for (int o = 32; o > 0; o >>= 1) s += __shfl_down(s, o, 64);
    __shared__ float ws4[4];
    if ((threadIdx.x & 63) == 0) ws4[threadIdx.x >> 6] = s;
    __syncthreads();
    if (threadIdx.x == 0) {
        float t = ws4[0] + ws4[1] + ws4[2] + ws4[3];
        norms[b * 256 + ch] = fmaxf(sqrtf(t), 1e-12f);
    }
}

// ---------- Gram partials: Spart[b,h,slot,dq,dk], slot = sp*4+wid ----------
__global__ __launch_bounds__(256)
void gram_kernel(const unsigned short* __restrict__ qkv, float* __restrict__ Spart)
{
    int h = blockIdx.x, b = blockIdx.y, sp = blockIdx.z;   // sp: 0..7
    int wid = threadIdx.x >> 6, lane = threadIdx.x & 63;
    int ln16 = lane & 15, quad = lane >> 4;
    int nbase = sp * 2048 + wid * 512;
    const unsigned short* qp = qkv + ((size_t)b * 384 + h * 16 + ln16) * NP;
    const unsigned short* kp = qkv + ((size_t)b * 384 + 128 + h * 16 + ln16) * NP;
    f32x4 acc = f32x4{0.f, 0.f, 0.f, 0.f};
    for (int i = 0; i < 512; i += 32) {
        int n = nbase + i + quad * 8;
        uint4 av = *(const uint4*)(qp + n);
        uint4 bv = *(const uint4*)(kp + n);
        acc = __builtin_amdgcn_mfma_f32_16x16x32_bf16(*(bf16x8*)&av, *(bf16x8*)&bv, acc, 0, 0, 0);
    }
    float* Sp = Spart + (((size_t)(b * NH + h) * 32) + sp * 4 + wid) * 256;
    #pragma unroll
    for (int r = 0; r < 4; ++r)
        Sp[(quad * 4 + r) * 16 + ln16] = acc[r];
}

// ---------- softmax over dk of (sum Spart)/(nq*nk)*temp ----------
__global__ __launch_bounds__(256)
void softmax_kernel(const float* __restrict__ Spart, const float* __restrict__ norms,
                    const unsigned short* __restrict__ temp, float* __restrict__ P)
{
    int bh = blockIdx.x;
    int b = bh >> 3, h = bh & 7;
    int t = threadIdx.x;            // 256 = 16x16
    int dq = t >> 4, dk = t & 15;
    float sacc = 0.f;
    const float* Sp = Spart + (size_t)bh * 32 * 256;
    #pragma unroll
    for (int j = 0; j < 32; ++j) sacc += Sp[j * 256 + t];
    float nq = norms[b * 256 + h * 16 + dq];
    float nk = norms[b * 256 + 128 + h * 16 + dk];
    float v = sacc / (nq * nk) * b2f(temp[h]);
    float m = v;
    #pragma unroll
    for (int o = 8; o > 0; o >>= 1) m = fmaxf(m, __shfl_xor(m, o, 16));
    float e = __expf(v - m);
    float s = e;
    #pragma unroll
    for (int o = 8; o > 0; o >>= 1) s += __shfl_xor(s, o, 16);
    P[(size_t)bh * 256 + t] = e / s;
}

// ---------- out[b, h*16+dq, n..n+3] = sum_e P[dq,e] * v[e,n..n+3] ----------
__global__ __launch_bounds__(256)
void attnv_kernel(const float* __restrict__ P, const unsigned short* __restrict__ qkv,
                  unsigned short* __restrict__ out)
{
    __shared__ float Ps[256];
    int h = blockIdx.y, b = blockIdx.z;
    Ps[threadIdx.x] = P[((size_t)b * NH + h) * 256 + threadIdx.x];
    __syncthreads();
    int n = (blockIdx.x * 256 + threadIdx.x) * 4;     // grid.x = NP/1024
    const unsigned short* vp = qkv + ((size_t)b * 384 + 256 + h * 16) * NP + n;
    float o[16][4];
    #pragma unroll
    for (int d = 0; d < 16; ++d)
        #pragma unroll
        for (int j = 0; j < 4; ++j) o[d][j] = 0.f;
    #pragma unroll
    for (int e = 0; e < 16; ++e) {
        union { uint2 v; unsigned short u[4]; } cv;
        cv.v = *(const uint2*)(vp + (size_t)e * NP);
        float v0 = b2f(cv.u[0]), v1 = b2f(cv.u[1]), v2 = b2f(cv.u[2]), v3 = b2f(cv.u[3]);
        #pragma unroll
        for (int d = 0; d < 16; ++d) {
            float p = Ps[d * 16 + e];
            o[d][0] += p * v0; o[d][1] += p * v1; o[d][2] += p * v2; o[d][3] += p * v3;
        }
    }
    unsigned short* op = out + ((size_t)b * C + h * 16) * NP + n;
    #pragma unroll
    for (int d = 0; d < 16; ++d) {
        union { uint2 v; unsigned short u[4]; } res;
        #pragma unroll
        for (int j = 0; j < 4; ++j) res.u[j] = f2b(o[d][j]);
        *(uint2*)(op + (size_t)d * NP) = res.v;
    }
}

// ---------- pipeline ----------
struct Bufs {
    float* xmid;            // nb*C*NP fp32 (trunk after MDTA)
    unsigned short* y;      // nb*C*NP bf16
    unsigned short* big;    // nb*512*NP bf16 (qkv1 / hdn)
    unsigned short* mid;    // nb*384*NP bf16 (qkv2 / gate out)
    float* norms;           // nb*256
    float* Spart;           // nb*NH*32*256
    float* P;               // nb*NH*256
};

static void run_pipeline(const float* x_f32, float* out_f32,
                         const unsigned short* w,    // packed bf16 weights
                         const Bufs& B, int nb, hipStream_t stream)
{
    const unsigned short* ln1_w   = w + 0;
    const unsigned short* ln1_b   = w + 128;
    const unsigned short* temp    = w + 256;
    const unsigned short* qkv_p_w = w + 272;
    const unsigned short* qkv_d_w = w + 49424;
    const unsigned short* proj_w  = w + 52880;
    const unsigned short* ln2_w   = w + 69264;
    const unsigned short* ln2_b   = w + 69392;
    const unsigned short* g1_w    = w + 69520;
    const unsigned short* gd_w    = w + 135056;
    const unsigned short* g2_w    = w + 139664;

    // ---- MDTA ----
    ln_kernel<<<nb * NP / 64, 256, 0, stream>>>(x_f32, ln1_w, ln1_b, B.y);
    gemm_pconv<128, 0><<<dim3(NP / 128, 3, nb), 256, 0, stream>>>(qkv_p_w, B.y, B.big, nullptr, 384);
    dwconv3_kernel<<<nb * 384 * NP / 2048, 256, 0, stream>>>(B.big, qkv_d_w, B.mid, 384);
    sumsq_kernel<<<dim3(256, nb), 256, 0, stream>>>(B.mid, B.norms);
    gram_kernel<<<dim3(NH, nb, 8), 256, 0, stream>>>(B.mid, B.Spart);
    softmax_kernel<<<nb * NH, 256, 0, stream>>>(B.Spart, B.norms, temp, B.P);
    attnv_kernel<<<dim3(NP / 1024, NH, nb), 256, 0, stream>>>(B.P, B.mid, B.y);
    gemm_pconv<128, 1><<<dim3(NP / 128, 1, nb), 256, 0, stream>>>(proj_w, B.y, B.xmid, x_f32, 128);

    // ---- GDFN ----
    ln_kernel<<<nb * NP / 64, 256, 0, stream>>>(B.xmid, ln2_w, ln2_b, B.y);
    gemm_pconv<128, 0><<<dim3(NP / 128, 4, nb), 256, 0, stream>>>(g1_w, B.y, B.big, nullptr, 512);
    dwgelu_kernel<<<nb * 256 * NP / 2048, 256, 0, stream>>>(B.big, gd_w, B.mid);
    gemm_pconv<256, 1><<<dim3(NP / 128, 1, nb), 256, 0, stream>>>(g2_w, B.mid, out_f32, B.xmid, 128);
}

extern "C" void kernel_launch(void* const* d_in, const int* in_sizes, int n_in,
                              void* d_out, int out_size, void* d_ws, size_t ws_size,
                              hipStream_t stream)
{
    (void)in_sizes; (void)n_in; (void)out_size;
    const float* x = (const float*)d_in[0];
    char* ws = (char*)d_ws;

    size_t off = 0;
    unsigned short* wpack = (unsigned short*)(ws + off);
    off += (size_t)kWTotal * 2;
    off = (off + 255) & ~(size_t)255;
    size_t header = off;

    auto layout = [&](int nb, size_t o, Bufs& B) -> size_t {
        B.xmid = (float*)(ws + o);           o += (size_t)nb * C * NP * 4;
        B.y    = (unsigned short*)(ws + o);  o += (size_t)nb * C * NP * 2;
        B.big  = (unsigned short*)(ws + o);  o += (size_t)nb * 512 * NP * 2;
        B.mid  = (unsigned short*)(ws + o);  o += (size_t)nb * 384 * NP * 2;
        B.norms = (float*)(ws + o);          o += (size_t)nb * 256 * 4;
        B.Spart = (float*)(ws + o);          o += (size_t)nb * NH * 32 * 256 * 4;
        B.P     = (float*)(ws + o);          o += (size_t)nb * NH * 256 * 4;
        return o;
    };

    // ---- convert weights fp32 -> packed bf16 ----
    Ptr11 P;
    for (int i = 0; i < 11; ++i) P.p[i] = (const float*)d_in[i + 1];
    cvt_w_kernel<<<dim3(256, 11), 256, 0, stream>>>(P, wpack);

    Bufs Bfull;
    size_t need_full = layout(4, header, Bfull);

    if (ws_size >= need_full) {
        run_pipeline(x, (float*)d_out, wpack, Bfull, 4, stream);
    } else {
        Bufs B1;
        layout(1, header, B1);
        for (int b = 0; b < 4; ++b) {
            run_pipeline(x + (size_t)b * C * NP,
                         (float*)d_out + (size_t)b * C * NP,
                         wpack, B1, 1, stream);
        }
    }
}